// Round 8
// baseline (112.246 us; speedup 1.0000x reference)
//
#include <hip/hip_runtime.h>
#include <math.h>

// Problem constants (fixed by setup_inputs): B=4, N=M=P=2048, NS=1024.
// out = [4,2048,2048] fp32, out_size = 16777216 floats.
//
// R5 change vs 111.5us baseline:
//  * nn_kernel: 8 a-points/thread (was 4). Halves LDS broadcast demand per
//    VALU op (1 ds_read_b128 per 32 VALU instead of per 16) -- theory: the
//    b128 broadcast pipe (~12cyc) was the limiter at 1-read-per-8cyc demand.
//    416 blocks x 2048-pt a-tiles (was 832 x 1024).
//  * reduce_kernel: 1024 threads/block, 1 point/thread (was 256 thr x 4 pts)
//    -> 576 waves instead of 144 for latency hiding of the 32-deep gather.
//  * out_kernel: UNCHANGED (control).
//
// nn job table (416 blocks; a_tile = 2048 pts, b_tile = 256 pts):
//   [0,128)    cd dir1:  A=pc1_0(8192) vs B=pc2(8192)    4 at x 32 bt
//   [128,256)  cd dir2:  A=pc2(8192)   vs B=pc1_0(8192)  4 at x 32 bt
//   [256,320)  seed dir1:A=pc1_1(4096) vs B=pc2(8192)    2 at x 32 bt
//   [320,384)  seed dir2:A=pc2(8192)   vs B=pc1_1(4096)  4 at x 16 bt
//   [384,416)  conf:     A=pc3[b](2048) vs B=pc2[b](2048) per batch 1 at x 8 bt
// Block bid writes its 2048 partial clamped-d2 values to part[bid*2048 ..).

constexpr int OUT_TOTAL  = 4 * 2048 * 2048;
constexpr int PART_TOTAL = 416 * 2048;              // 851968 floats, 3.4 MB
constexpr int PART_OFS   = OUT_TOTAL - PART_TOTAL;

// native vector type for __builtin_nontemporal_store (HIP_vector_type rejected)
typedef float nfloat4 __attribute__((ext_vector_type(4)));

__global__ __launch_bounds__(256) void nn_kernel(
    const float* __restrict__ A0,   // pc1_0 flat (8192 pts)
    const float* __restrict__ A1,   // pc1_1 flat (4096 pts)
    const float* __restrict__ P2,   // pc2   flat (8192 pts / 4 batches x 2048)
    const float* __restrict__ P3,   // pc3   (4 x 2048 pts)
    float* __restrict__ part)
{
    __shared__ float4 lds[256];     // (bx, by, bz, -0.5*|b|^2)
    int bid = blockIdx.x;
    const float* A; const float* Bp; int at; int btile;
    if (bid < 128)      { int l = bid;       A = A0; Bp = P2; at = l >> 5; btile = l & 31; }
    else if (bid < 256) { int l = bid - 128; A = P2; Bp = A0; at = l >> 5; btile = l & 31; }
    else if (bid < 320) { int l = bid - 256; A = A1; Bp = P2; at = l >> 5; btile = l & 31; }
    else if (bid < 384) { int l = bid - 320; A = P2; Bp = A1; at = l >> 4; btile = l & 15; }
    else { int l = bid - 384; int b = l >> 3; btile = l & 7; at = 0;
           A = P3 + b * 6144; Bp = P2 + b * 6144; }

    {
        const float* s = Bp + (btile * 256 + threadIdx.x) * 3;
        float bx = s[0], by = s[1], bz = s[2];
        float nb2 = -0.5f * fmaf(bx, bx, fmaf(by, by, bz * bz));
        lds[threadIdx.x] = make_float4(bx, by, bz, nb2);
    }

    // 8 a-points per thread (24 consecutive floats, 16B-aligned -> 6x float4)
    int a_base = at * 2048 + threadIdx.x * 8;
    const float4* av = (const float4*)(A + a_base * 3);
    float4 v0 = av[0], v1 = av[1], v2 = av[2], v3 = av[3], v4 = av[4], v5 = av[5];
    float ax[8], ay[8], az[8], a2[8], mx[8];
    ax[0]=v0.x; ay[0]=v0.y; az[0]=v0.z;
    ax[1]=v0.w; ay[1]=v1.x; az[1]=v1.y;
    ax[2]=v1.z; ay[2]=v1.w; az[2]=v2.x;
    ax[3]=v2.y; ay[3]=v2.z; az[3]=v2.w;
    ax[4]=v3.x; ay[4]=v3.y; az[4]=v3.z;
    ax[5]=v3.w; ay[5]=v4.x; az[5]=v4.y;
    ax[6]=v4.z; ay[6]=v4.w; az[6]=v5.x;
    ax[7]=v5.y; ay[7]=v5.z; az[7]=v5.w;
    #pragma unroll
    for (int k = 0; k < 8; k++) {
        a2[k] = fmaf(ax[k], ax[k], fmaf(ay[k], ay[k], az[k]*az[k]));
        mx[k] = -3.4e38f;
    }
    __syncthreads();

    // maximize (a.b - 0.5|b|^2); d2 = max(|a|^2 - 2*mx, 0). 4 VALU ops/pair;
    // 32 VALU per ds_read_b128 -> LDS demand 1 per 16 cyc < ~12 cyc pipe rate.
    #pragma unroll 4
    for (int j = 0; j < 256; j++) {
        float4 b = lds[j];
        #pragma unroll
        for (int k = 0; k < 8; k++) {
            float u = fmaf(az[k], b.z, b.w);
            u = fmaf(ay[k], b.y, u);
            u = fmaf(ax[k], b.x, u);
            mx[k] = fmaxf(mx[k], u);
        }
    }
    float4 o0, o1;
    o0.x = fmaxf(fmaf(-2.f, mx[0], a2[0]), 0.f);
    o0.y = fmaxf(fmaf(-2.f, mx[1], a2[1]), 0.f);
    o0.z = fmaxf(fmaf(-2.f, mx[2], a2[2]), 0.f);
    o0.w = fmaxf(fmaf(-2.f, mx[3], a2[3]), 0.f);
    o1.x = fmaxf(fmaf(-2.f, mx[4], a2[4]), 0.f);
    o1.y = fmaxf(fmaf(-2.f, mx[5], a2[5]), 0.f);
    o1.z = fmaxf(fmaf(-2.f, mx[6], a2[6]), 0.f);
    o1.w = fmaxf(fmaf(-2.f, mx[7], a2[7]), 0.f);
    float4* op = (float4*)(part + bid * 2048 + threadIdx.x * 8);
    op[0] = o0;
    op[1] = o1;
}

// 36 blocks x 1024 threads; 1 point per thread. Group g -> region:
//   g<8:   cd1   at=g>>1        base=(at*32)*2048      bt=32 scale=0.5/8192
//   <16:   cd2   at=(g-8)>>1    base=(128+at*32)*2048  bt=32 scale=0.5/8192
//   <20:   seed1 at=(g-16)>>1   base=(256+at*32)*2048  bt=32 scale=1/4096
//   <28:   seed2 at=(g-20)>>1   base=(320+at*16)*2048  bt=16 scale=1/8192
//   <36:   conf  b=(g-28)>>1    base=(384+b*8)*2048    bt=8  scale=1/8192 (MSE)
// plus (g&1)*1024 half-tile offset within the 2048-pt a-tile.
__global__ __launch_bounds__(1024) void reduce_kernel(
    const float* __restrict__ part,
    const float* __restrict__ conf_in,   // pc1_3, 8192 values
    float* __restrict__ ws)
{
    int g = blockIdx.x;
    int tid = threadIdx.x;
    int base, bt; float scale; bool isconf = false;
    if (g < 8)       { int at = g >> 1;            base = (at * 32) * 2048       + (g & 1) * 1024; bt = 32; scale = 0.5f / 8192.f; }
    else if (g < 16) { int l = g - 8;  int at = l >> 1; base = (128 + at * 32) * 2048 + (l & 1) * 1024; bt = 32; scale = 0.5f / 8192.f; }
    else if (g < 20) { int l = g - 16; int at = l >> 1; base = (256 + at * 32) * 2048 + (l & 1) * 1024; bt = 32; scale = 1.f / 4096.f; }
    else if (g < 28) { int l = g - 20; int at = l >> 1; base = (320 + at * 16) * 2048 + (l & 1) * 1024; bt = 16; scale = 1.f / 8192.f; }
    else             { int l = g - 28; int b = l >> 1;  base = (384 + b * 8) * 2048   + (l & 1) * 1024; bt = 8;  scale = 1.f / 8192.f; isconf = true; }

    float m = 3.4e38f;
    const float* p = part + base + tid;
    #pragma unroll 4
    for (int t = 0; t < bt; t++, p += 2048) m = fminf(m, p[0]);
    float d = sqrtf(m);
    float sum;
    if (!isconf) {
        sum = d;
    } else {
        float e = conf_in[(g - 28) * 1024 + tid] - __expf(-d);
        sum = e * e;
    }
    #pragma unroll
    for (int ofs = 32; ofs > 0; ofs >>= 1) sum += __shfl_down(sum, ofs);
    __shared__ float red[16];
    if ((tid & 63) == 0) red[tid >> 6] = sum;
    __syncthreads();
    if (tid == 0) {
        float tot = 0.f;
        #pragma unroll
        for (int i = 0; i < 16; i++) tot += red[i];
        ws[g] = tot * scale;
    }
}

// out[b,n,m] = S + 0.5 * dist(pc1_0[b,n], pc2[b,m]).  UNCHANGED (control).
__global__ __launch_bounds__(256) void out_kernel(
    const float* __restrict__ pc1_0,
    const float* __restrict__ pc2,
    const float* __restrict__ wsp,
    float* __restrict__ out)
{
    int blk = blockIdx.x;            // 1024 blocks
    int batch = blk >> 8;
    int n8 = blk & 255;
    int tid = threadIdx.x;
    float S = 0.f;
    #pragma unroll
    for (int t = 0; t < 36; t++) S += wsp[t];   // uniform -> s_loads
    const float* bb = pc2 + batch * 6144;
    float bx[8], by[8], bz[8];
    {
        const float4* p = (const float4*)(bb + tid * 12);
        float4 u0 = p[0], u1 = p[1], u2 = p[2];
        bx[0]=u0.x; by[0]=u0.y; bz[0]=u0.z;
        bx[1]=u0.w; by[1]=u1.x; bz[1]=u1.y;
        bx[2]=u1.z; by[2]=u1.w; bz[2]=u2.x;
        bx[3]=u2.y; by[3]=u2.z; bz[3]=u2.w;
    }
    {
        const float4* p = (const float4*)(bb + 3072 + tid * 12);
        float4 u0 = p[0], u1 = p[1], u2 = p[2];
        bx[4]=u0.x; by[4]=u0.y; bz[4]=u0.z;
        bx[5]=u0.w; by[5]=u1.x; bz[5]=u1.y;
        bx[6]=u1.z; by[6]=u1.w; bz[6]=u2.x;
        bx[7]=u2.y; by[7]=u2.z; bz[7]=u2.w;
    }
    const float* arow = pc1_0 + batch * 6144 + n8 * 24;  // 8 rows x 3 (uniform)
    float* ob = out + (long)((batch << 11) + (n8 << 3)) * 2048 + tid * 4;
    #pragma unroll
    for (int r = 0; r < 8; r++) {
        float axx = arow[r*3], ayy = arow[r*3+1], azz = arow[r*3+2];
        float o[8];
        #pragma unroll
        for (int k = 0; k < 8; k++) {
            float dx = axx - bx[k], dy = ayy - by[k], dz = azz - bz[k];
            float d2 = fmaf(dx, dx, fmaf(dy, dy, dz*dz));
            o[k] = fmaf(0.5f, sqrtf(d2), S);
        }
        nfloat4 lo = { o[0], o[1], o[2], o[3] };
        nfloat4 hi = { o[4], o[5], o[6], o[7] };
        __builtin_nontemporal_store(lo, (nfloat4*)(ob + r * 2048));
        __builtin_nontemporal_store(hi, (nfloat4*)(ob + r * 2048 + 1024));
    }
}

extern "C" void kernel_launch(void* const* d_in, const int* in_sizes, int n_in,
                              void* d_out, int out_size, void* d_ws, size_t ws_size,
                              hipStream_t stream) {
    const float* pc1_0 = (const float*)d_in[0];  // [4,2048,3]
    const float* pc1_1 = (const float*)d_in[1];  // [4,1024,3]
    const float* pc1_3 = (const float*)d_in[2];  // [4,2048,1]
    const float* pc2   = (const float*)d_in[3];  // [4,2048,3]
    const float* pc3   = (const float*)d_in[4];  // [4,2048,3]
    float* out = (float*)d_out;
    float* ws  = (float*)d_ws;                   // ws[0..35]: scaled partial sums
    float* part = out + PART_OFS;                // partial-min scratch in d_out tail

    nn_kernel<<<416, 256, 0, stream>>>(pc1_0, pc1_1, pc2, pc3, part);
    reduce_kernel<<<36, 1024, 0, stream>>>(part, pc1_3, ws);
    out_kernel<<<1024, 256, 0, stream>>>(pc1_0, pc2, ws, out);
}